// Round 9
// baseline (604.963 us; speedup 1.0000x reference)
//
#include <hip/hip_runtime.h>
#include <hip/hip_bf16.h>

// Problem dims (fixed by reference setup_inputs)
#define NN 32768
#define HH 768
#define HEADS 2
#define EE 131072
#define HC (HEADS*HH)      // 1536
#define ETOT (EE + NN)     // 163840 (edges + self loops)
#define NEG_SLOPE 0.2f
#define GK 768             // GEMM K
#define GNF 3072           // fused GEMM N ([W_l | W_r] cols)

typedef __bf16 bf16x8 __attribute__((ext_vector_type(8)));
typedef float f32x4 __attribute__((ext_vector_type(4)));
typedef unsigned short u16x8 __attribute__((ext_vector_type(8)));

// bf16 <-> f32 helpers (RNE, finite data only)
__device__ __forceinline__ float b2f(unsigned short u) {
  union { float f; unsigned int i; } v; v.i = ((unsigned int)u) << 16; return v.f;
}
__device__ __forceinline__ unsigned short f2b(float f) {
  unsigned int x = __float_as_uint(f);
  x += 0x7fff + ((x >> 16) & 1);
  return (unsigned short)(x >> 16);
}
__device__ __forceinline__ void glds16(const unsigned short* g, unsigned short* l) {
  __builtin_amdgcn_global_load_lds(
      (const __attribute__((address_space(1))) unsigned int*)g,
      (__attribute__((address_space(3))) unsigned int*)l, 16, 0, 0);
}

// ---------------- zero a float region ----------------
__global__ __launch_bounds__(256) void zero_f32(float* __restrict__ p, int n) {
  int i = blockIdx.x * blockDim.x + threadIdx.x;
  int st = gridDim.x * blockDim.x;
  for (; i < n; i += st) p[i] = 0.f;
}

// ---------------- emb f32 -> bf16 (vectorized, 8 elems/thread/iter) ----------
__global__ __launch_bounds__(256) void cvt_f32_bf16(
    const float* __restrict__ in, unsigned short* __restrict__ out, int n8) {
  int i = blockIdx.x * blockDim.x + threadIdx.x;
  int st = gridDim.x * blockDim.x;
  for (; i < n8; i += st) {
    float4 a = *(const float4*)(in + (size_t)i * 8);
    float4 b = *(const float4*)(in + (size_t)i * 8 + 4);
    u16x8 w;
    w[0] = f2b(a.x); w[1] = f2b(a.y); w[2] = f2b(a.z); w[3] = f2b(a.w);
    w[4] = f2b(b.x); w[5] = f2b(b.y); w[6] = f2b(b.z); w[7] = f2b(b.w);
    *(u16x8*)(out + (size_t)i * 8) = w;
  }
}

// ------------- W[768][1536] f32 -> Wt[1536][768] bf16 (transpose+convert) ----
__global__ __launch_bounds__(256) void transpose_bf16(
    const float* __restrict__ W, unsigned short* __restrict__ Wt) {
  __shared__ float tile[32][33];
  int n0 = blockIdx.x * 32, k0 = blockIdx.y * 32;
  int tx = threadIdx.x & 31, ty = threadIdx.x >> 5;  // 32 x 8
#pragma unroll
  for (int s = 0; s < 4; ++s)
    tile[ty + s * 8][tx] = W[(size_t)(k0 + ty + s * 8) * HC + n0 + tx];
  __syncthreads();
#pragma unroll
  for (int s = 0; s < 4; ++s)
    Wt[(size_t)(n0 + ty + s * 8) * GK + k0 + tx] = f2b(tile[tx][ty + s * 8]);
}

// ======== FAST GEMM: 256x256, 8 waves, 1-barrier-per-phase pipeline ==========
// C[32768][3072] = Ab * Bt^T.  BK=64; 4 phases/K-tile; per phase:
//   stage (0 or 4 gload_lds) -> ds_reads -> [VM on staging phases] -> barrier
//   -> setprio MFMA.
// VM is STAGER-side (p1/p3, before the barrier): each wave's VM(8) drains the
// loads for the tile-half read in the NEXT read phase; the barrier orders that
// drain before any wave's ds_reads of it (cross-wave guarantee).  Outstanding
// per wave: 12 steady (3 half-tiles x 4) -> VM(8); tail VM(8)/VM(4)/VM(0).
// Write-safety: each stage targets a slot last READ 2 phases earlier; a reader
// passing barrier p-1 has issued MFMA_{p-2} whose lgkm wait retired its reads.
// Epilogue: operand-swapped MFMA (D rows = n, cols = m) -> lane holds 4
// consecutive n -> packed 8B ushort4 stores.
__global__ __launch_bounds__(512, 2) void gemm_mfma2(
    const unsigned short* __restrict__ Ab, const unsigned short* __restrict__ Bt,
    unsigned short* __restrict__ C) {
  __shared__ unsigned short Abuf[2][16384];  // [buf][rhalf*8192+kh*4096+q*1024+row*8]
  __shared__ unsigned short Bbuf[2][16384];
  int tid = threadIdx.x, lane = tid & 63, w = tid >> 6;
  int wr = w >> 2, wc = w & 3;          // wave grid 2M x 4N
  int ql = lane >> 4, ml = lane & 15;
  // XCD-bijective walk: 1536 = 8 XCD x (16 m x 12 n), n fastest
  int b = blockIdx.x;
  int xcd = b & 7, loc = b >> 3;
  int m_blk = xcd * 16 + loc / 12, n_blk = loc % 12;
  int m0 = m_blk * 256, n0 = n_blk * 256;

  // staging mapping: thread covers chunk (q=w>>1, row=(w&1)*64+lane)
  int qd = w >> 1, rloc = (w & 1) * 64 + lane;
  const unsigned short* sA0 = Ab + (size_t)(m0 + rloc) * GK + qd * 8;
  const unsigned short* sA1 = Ab + (size_t)(m0 + 128 + rloc) * GK + qd * 8;
  const unsigned short* sB0 = Bt + (size_t)(n0 + rloc) * GK + qd * 8;
  const unsigned short* sB1 = Bt + (size_t)(n0 + 128 + rloc) * GK + qd * 8;
  int lof0 = qd * 1024 + rloc * 8;
  // read bases
  int A0 = ((wr * 8 + ql) * 128 + ml) * 8;
  int B0 = (((wc >> 1) * 8 + ql) * 128 + (wc & 1) * 64 + ml) * 8;

  f32x4 acc[8][4] = {};
  bf16x8 a[4], bb[4];

#define SA(s_, kt_, kh_) {                                              \
    glds16(sA0 + (kt_)*64 + (kh_)*32, &Abuf[s_][(kh_)*4096 + lof0]);    \
    glds16(sA1 + (kt_)*64 + (kh_)*32, &Abuf[s_][(kh_)*4096 + lof0 + 8192]); }
#define SB(s_, kt_, kh_) {                                              \
    glds16(sB0 + (kt_)*64 + (kh_)*32, &Bbuf[s_][(kh_)*4096 + lof0]);    \
    glds16(sB1 + (kt_)*64 + (kh_)*32, &Bbuf[s_][(kh_)*4096 + lof0 + 8192]); }
#define LDA_(mh_, kh_, s_) { _Pragma("unroll") for (int i = 0; i < 4; ++i) \
    a[i] = *(const bf16x8*)&Abuf[s_][A0 + (kh_)*4096 + ((mh_)*4 + i)*128]; }
#define LDB_(kh_, s_) { _Pragma("unroll") for (int j = 0; j < 4; ++j) \
    bb[j] = *(const bf16x8*)&Bbuf[s_][B0 + (kh_)*4096 + j*128]; }
// operand-swapped: D rows = n (frag j), cols = m (frag mh*4+i)
#define MM(mh_) { _Pragma("unroll") for (int i = 0; i < 4; ++i) {       \
    _Pragma("unroll") for (int j = 0; j < 4; ++j)                       \
      acc[(mh_)*4+i][j] = __builtin_amdgcn_mfma_f32_16x16x32_bf16(      \
          bb[j], a[i], acc[(mh_)*4+i][j], 0, 0, 0); } }
#define SBR __builtin_amdgcn_sched_barrier(0)
#define BARRIER { SBR; __builtin_amdgcn_s_barrier(); SBR; }
#define VM(n_) { asm volatile("s_waitcnt vmcnt(" #n_ ")" ::: "memory"); }
#define PMM(mh_) { __builtin_amdgcn_s_setprio(1); MM(mh_); __builtin_amdgcn_s_setprio(0); }

  // prologue: T0 kh0, T0 kh1, T1 kh0 (12 loads in flight); land T0 kh0
  SA(0, 0, 0); SB(0, 0, 0);
  SA(0, 0, 1); SB(0, 0, 1);
  SA(1, 1, 0); SB(1, 1, 0);
  VM(8); BARRIER;

#pragma unroll 1
  for (int kt = 0; kt < 10; ++kt) {
    int s = kt & 1, sn = s ^ 1;
    // p0: read tile kt kh0 (landed: VM(8) before previous barrier)
    LDB_(0, s); LDA_(0, 0, s);
    BARRIER; PMM(0);
    // p1: stage T(kt+1) kh1; read mh1 kh0; VM lands T(kt) kh1 for p2
    SA(sn, kt + 1, 1); SB(sn, kt + 1, 1);
    LDA_(1, 0, s);
    VM(8); BARRIER; PMM(1);
    // p2: read tile kt kh1
    LDB_(1, s); LDA_(0, 1, s);
    BARRIER; PMM(0);
    // p3: stage T(kt+2) kh0; read mh1 kh1; VM lands T(kt+1) kh0 for next p0
    SA(s, kt + 2, 0); SB(s, kt + 2, 0);
    LDA_(1, 1, s);
    VM(8); BARRIER; PMM(1);
  }
  // kt = 10 (s=0): only T11 kh1 stage remains
  LDB_(0, 0); LDA_(0, 0, 0); BARRIER; PMM(0);
  SA(1, 11, 1); SB(1, 11, 1); LDA_(1, 0, 0); VM(8); BARRIER; PMM(1);
  LDB_(1, 0); LDA_(0, 1, 0); BARRIER; PMM(0);
  LDA_(1, 1, 0); VM(4); BARRIER; PMM(1);
  // kt = 11 (s=1): no stages
  LDB_(0, 1); LDA_(0, 0, 1); BARRIER; PMM(0);
  LDA_(1, 0, 1); VM(0); BARRIER; PMM(1);
  LDB_(1, 1); LDA_(0, 1, 1); BARRIER; PMM(0);
  LDA_(1, 1, 1); BARRIER; PMM(1);

  // epilogue (swapped layout): lane holds n = ql*4+rg (consecutive) per frag,
  // m = m0 + wr*128 + mf*16 + ml  ->  one 8B packed store per frag
#pragma unroll
  for (int mf = 0; mf < 8; ++mf) {
    int m = m0 + wr * 128 + mf * 16 + ml;
    unsigned short* Cp = C + (size_t)m * GNF + n0 + wc * 64 + ql * 4;
#pragma unroll
    for (int j = 0; j < 4; ++j) {
      ushort4 v;
      v.x = f2b(acc[mf][j][0]); v.y = f2b(acc[mf][j][1]);
      v.z = f2b(acc[mf][j][2]); v.w = f2b(acc[mf][j][3]);
      *(ushort4*)(Cp + j * 16) = v;
    }
  }
#undef SA
#undef SB
#undef LDA_
#undef LDB_
#undef MM
#undef BARRIER
#undef VM
#undef PMM
}

// ======== FALLBACK GEMM (R4-proven): fp32 A reg-staged, bf16 B gload_lds =====
__global__ __launch_bounds__(256) void gemm_mfma(
    const float* __restrict__ A, const unsigned short* __restrict__ Bt,
    unsigned short* __restrict__ C) {
  __shared__ unsigned short Abuf[2][4096];
  __shared__ unsigned short Bbuf[2][4096];
  int tid = threadIdx.x;
  int lane = tid & 63;
  int wv = tid >> 6;
  int wr = wv >> 1, wc = wv & 1;
  int b = blockIdx.x;
  int lid = (b & 7) * 768 + (b >> 3);
  int m_blk = lid / 24, n_blk = lid % 24;
  int m0 = m_blk * 128, n0 = n_blk * 128;
  int ql = lane >> 4, ml = lane & 15;
  int ar = tid >> 1, ah = tid & 1;
  const float* Ag = A + (size_t)(m0 + ar) * GK + ah * 16;
  int j0 = wv * 128 + lane;
  int j1 = j0 + 64;
  int q0 = j0 >> 7, r0 = j0 & 127;
  int q1 = j1 >> 7, r1 = j1 & 127;
  const unsigned short* Bg0 = Bt + (size_t)(n0 + r0) * GK + q0 * 8;
  const unsigned short* Bg1 = Bt + (size_t)(n0 + r1) * GK + q1 * 8;
  int ldsb0 = (wv * 128) * 8;
  int ldsb1 = (wv * 128 + 64) * 8;

  f32x4 acc[4][4] = {};
  float4 av[4];

#define LOAD_A(k0_) {                                                   \
    av[0] = *(const float4*)(Ag + (k0_));                               \
    av[1] = *(const float4*)(Ag + (k0_) + 4);                           \
    av[2] = *(const float4*)(Ag + (k0_) + 8);                           \
    av[3] = *(const float4*)(Ag + (k0_) + 12); }

#define WRITE_A(nb) {                                                   \
    bf16x8 w0, w1;                                                      \
    w0[0]=(__bf16)av[0].x; w0[1]=(__bf16)av[0].y; w0[2]=(__bf16)av[0].z; w0[3]=(__bf16)av[0].w; \
    w0[4]=(__bf16)av[1].x; w0[5]=(__bf16)av[1].y; w0[6]=(__bf16)av[1].z; w0[7]=(__bf16)av[1].w; \
    w1[0]=(__bf16)av[2].x; w1[1]=(__bf16)av[2].y; w1[2]=(__bf16)av[2].z; w1[3]=(__bf16)av[2].w; \
    w1[4]=(__bf16)av[3].x; w1[5]=(__bf16)av[3].y; w1[6]=(__bf16)av[3].z; w1[7]=(__bf16)av[3].w; \
    *(bf16x8*)&Abuf[nb][(2*ah) * 1024 + ar * 8] = w0;                   \
    *(bf16x8*)&Abuf[nb][(2*ah + 1) * 1024 + ar * 8] = w1; }

#define STAGE_B(nb, k0_) {                      \
    glds16(Bg0 + (k0_), &Bbuf[nb][ldsb0]);      \
    glds16(Bg1 + (k0_), &Bbuf[nb][ldsb1]); }

  LOAD_A(0);
  STAGE_B(0, 0);
  WRITE_A(0);

  const int NT = GK / 32;  // 24
  for (int t = 0; t < NT; ++t) {
    int cur = t & 1, nxt = cur ^ 1;
    __syncthreads();
    if (t + 1 < NT) {
      LOAD_A((t + 1) * 32);
      STAGE_B(nxt, (t + 1) * 32);
    }
    bf16x8 a[4], bfr[4];
#pragma unroll
    for (int i = 0; i < 4; ++i)
      a[i] = *(const bf16x8*)&Abuf[cur][ql * 1024 + (wr * 64 + i * 16 + ml) * 8];
#pragma unroll
    for (int j = 0; j < 4; ++j)
      bfr[j] = *(const bf16x8*)&Bbuf[cur][ql * 1024 + (wc * 64 + j * 16 + ml) * 8];
#pragma unroll
    for (int i = 0; i < 4; ++i)
#pragma unroll
      for (int j = 0; j < 4; ++j)
        acc[i][j] = __builtin_amdgcn_mfma_f32_16x16x32_bf16(a[i], bfr[j], acc[i][j], 0, 0, 0);
    if (t + 1 < NT) WRITE_A(nxt);
  }

#pragma unroll
  for (int i = 0; i < 4; ++i)
#pragma unroll
    for (int j = 0; j < 4; ++j)
#pragma unroll
      for (int rg = 0; rg < 4; ++rg) {
        int m = m0 + wr * 64 + i * 16 + ql * 4 + rg;
        int n = n0 + wc * 64 + j * 16 + ml;
        C[(size_t)m * GNF + n] = f2b(acc[i][j][rg]);
      }
}

// ------------- edge logits: wave per edge, w = exp(logit), denom scatter -----
// x row n = [x_l(n) 1536 | x_r(n) 1536], stride 3072.
__global__ __launch_bounds__(256) void edge_logits(
    const unsigned short* __restrict__ x,
    const int* __restrict__ edges, const float* __restrict__ att,
    float* __restrict__ wbuf, float* __restrict__ denom) {
  int wave = (int)((blockIdx.x * blockDim.x + threadIdx.x) >> 6);
  int lane = threadIdx.x & 63;
  if (wave >= ETOT) return;
  int src, dst;
  if (wave < EE) {
    src = edges[wave];
    dst = edges[EE + wave];
  } else {
    src = dst = wave - EE;
  }
  const unsigned short* pl = x + (size_t)src * GNF;          // x_l[src]
  const unsigned short* pr = x + (size_t)dst * GNF + HC;     // x_r[dst]
#pragma unroll
  for (int h = 0; h < HEADS; ++h) {
    float s = 0.f;
    const unsigned short* phl = pl + h * HH;
    const unsigned short* phr = pr + h * HH;
    const float* pa = att + h * HH;
#pragma unroll
    for (int it = 0; it < 3; ++it) {
      int d = (it * 64 + lane) * 4;
      ushort4 a = *(const ushort4*)(phl + d);
      ushort4 b = *(const ushort4*)(phr + d);
      float4 w = *(const float4*)(pa + d);
      float x0 = b2f(a.x) + b2f(b.x);
      float x1 = b2f(a.y) + b2f(b.y);
      float x2 = b2f(a.z) + b2f(b.z);
      float x3 = b2f(a.w) + b2f(b.w);
      x0 = x0 >= 0.f ? x0 : NEG_SLOPE * x0;
      x1 = x1 >= 0.f ? x1 : NEG_SLOPE * x1;
      x2 = x2 >= 0.f ? x2 : NEG_SLOPE * x2;
      x3 = x3 >= 0.f ? x3 : NEG_SLOPE * x3;
      s += x0 * w.x + x1 * w.y + x2 * w.z + x3 * w.w;
    }
#pragma unroll
    for (int off = 32; off; off >>= 1) s += __shfl_down(s, off);
    if (lane == 0) {
      float w = expf(s);
      wbuf[(size_t)wave * 2 + h] = w;
      atomicAdd(&denom[(size_t)dst * 2 + h], w);
    }
  }
}

// ------------- alpha -> per-source scalar coefficients (masked by dst) -------
__global__ __launch_bounds__(256) void alpha_scatter(
    const int* __restrict__ edges, const int* __restrict__ mask,
    const float* __restrict__ wbuf, const float* __restrict__ denom,
    float* __restrict__ c) {
  int e = blockIdx.x * blockDim.x + threadIdx.x;
  if (e >= ETOT) return;
  int src, dst;
  if (e < EE) {
    src = edges[e];
    dst = edges[EE + e];
  } else {
    src = dst = e - EE;
  }
  if (mask[dst]) {
    atomicAdd(&c[(size_t)src * 2 + 0], wbuf[(size_t)e * 2 + 0] / denom[(size_t)dst * 2 + 0]);
    atomicAdd(&c[(size_t)src * 2 + 1], wbuf[(size_t)e * 2 + 1] / denom[(size_t)dst * 2 + 1]);
  }
}

// ------------- count masked nodes (float; exact below 2^24) ------------------
__global__ __launch_bounds__(256) void count_mask(
    const int* __restrict__ mask, float* __restrict__ cnt) {
  int t = blockIdx.x * blockDim.x + threadIdx.x;
  int stride = gridDim.x * blockDim.x;
  float local = 0.f;
  for (int i = t; i < NN; i += stride) local += (mask[i] != 0) ? 1.f : 0.f;
#pragma unroll
  for (int off = 32; off; off >>= 1) local += __shfl_down(local, off);
  if ((threadIdx.x & 63) == 0 && local != 0.f) atomicAdd(cnt, local);
}

// ------------- t[h,k] = sum_n c[n,h] * emb[n,k]  (bf16 emb variant) ----------
__global__ __launch_bounds__(256) void c_emb_gemv_b(
    const unsigned short* __restrict__ embb, const float* __restrict__ c,
    float* __restrict__ t) {
  int tid = threadIdx.x;   // 256
  int b = blockIdx.x;      // 256 blocks x 128 rows
  float a0[3] = {}, a1[3] = {};
  int n0 = b * 128;
  for (int r = 0; r < 128; ++r) {
    int n = n0 + r;
    float c0 = c[(size_t)n * 2 + 0];
    float c1 = c[(size_t)n * 2 + 1];
    const unsigned short* row = embb + (size_t)n * HH;
#pragma unroll
    for (int k = 0; k < 3; ++k) {
      float v = b2f(row[tid + k * 256]);
      a0[k] += c0 * v;
      a1[k] += c1 * v;
    }
  }
#pragma unroll
  for (int k = 0; k < 3; ++k) {
    atomicAdd(&t[tid + k * 256], a0[k]);
    atomicAdd(&t[HH + tid + k * 256], a1[k]);
  }
}

// ------------- t[h,k] = sum_n c[n,h] * emb[n,k]  (fp32, fallback path) -------
__global__ __launch_bounds__(256) void c_emb_gemv(
    const float* __restrict__ emb, const float* __restrict__ c,
    float* __restrict__ t) {
  int tid = threadIdx.x;
  int b = blockIdx.x;
  float a0[3] = {}, a1[3] = {};
  int n0 = b * 128;
  for (int r = 0; r < 128; ++r) {
    int n = n0 + r;
    float c0 = c[(size_t)n * 2 + 0];
    float c1 = c[(size_t)n * 2 + 1];
    const float* row = emb + (size_t)n * HH;
#pragma unroll
    for (int k = 0; k < 3; ++k) {
      float v = row[tid + k * 256];
      a0[k] += c0 * v;
      a1[k] += c1 * v;
    }
  }
#pragma unroll
  for (int k = 0; k < 3; ++k) {
    atomicAdd(&t[tid + k * 256], a0[k]);
    atomicAdd(&t[HH + tid + k * 256], a1[k]);
  }
}

// ------------- pooled[h*768+d] = sum_k t[h,k] * W_l[k, h*768+d] --------------
__global__ __launch_bounds__(256) void pooled_gemv(
    const float* __restrict__ t, const float* __restrict__ W_l,
    float* __restrict__ pooled) {
  int idx = blockIdx.x * blockDim.x + threadIdx.x;  // 6*256 = 1536
  if (idx >= HC) return;
  int h = idx / HH;
  float s = 0.f;
  const float* tp = t + (size_t)h * HH;
  const float* wp = W_l + idx;
  for (int k = 0; k < HH; ++k) s += tp[k] * wp[(size_t)k * HC];
  pooled[idx] = s;
}

// ------------- finalize: psy -> classifier -> loss/pred/acc ------------------
__global__ __launch_bounds__(64) void finalize(
    const float* __restrict__ pooled, const float* __restrict__ cntp,
    const float* __restrict__ bias, const float* __restrict__ clsW,
    const float* __restrict__ clsb, const int* __restrict__ labels,
    float* __restrict__ out) {
  int lane = threadIdx.x;  // 64
  float cnt = *cntp;
  float inv = 1.f / (cnt + 1e-8f);
  __shared__ float lin[8];
  for (int lo = 0; lo < 8; ++lo) {
    int l = lo >> 1, o = lo & 1;
    float s = 0.f;
    for (int d = lane; d < HH; d += 64) {
      float psy = (0.5f * (pooled[d] + pooled[HH + d]) + cnt * bias[d]) * inv;
      s += psy * clsW[(size_t)l * HH * 2 + (size_t)d * 2 + o];
    }
#pragma unroll
    for (int off = 32; off; off >>= 1) s += __shfl_down(s, off);
    if (lane == 0) lin[lo] = s + clsb[lo];
  }
  __syncthreads();
  if (lane == 0) {
    float loss = 0.f, accv = 0.f;
    for (int l = 0; l < 4; ++l) {
      float a = lin[l * 2], bb = lin[l * 2 + 1];
      float m = fmaxf(a, bb);
      float ea = expf(a - m), eb = expf(bb - m);
      float inv2 = 1.f / (ea + eb);
      float p0 = ea * inv2, p1 = eb * inv2;
      // reference applies log_softmax to the PROBS (double-softmax quirk)
      float m2 = fmaxf(p0, p1);
      float lse = m2 + logf(expf(p0 - m2) + expf(p1 - m2));
      float lp0 = p0 - lse, lp1 = p1 - lse;
      int lab = labels[l];
      loss -= (lab == 1) ? lp1 : lp0;
      int pred = (p1 > p0) ? 1 : 0;  // argmax: first index on tie
      out[1 + l] = (float)pred;
      accv += (pred == lab) ? 1.f : 0.f;
    }
    out[0] = loss;
    out[5] = accv;
  }
}

// ---------------------------------------------------------------------------
extern "C" void kernel_launch(void* const* d_in, const int* in_sizes, int n_in,
                              void* d_out, int out_size, void* d_ws, size_t ws_size,
                              hipStream_t stream) {
  const float* emb   = (const float*)d_in[0];
  const int*   mask  = (const int*)d_in[1];
  const int*   edges = (const int*)d_in[2];
  const int*   labels= (const int*)d_in[3];
  const float* W_l   = (const float*)d_in[4];
  const float* W_r   = (const float*)d_in[5];
  const float* att   = (const float*)d_in[6];
  const float* gbias = (const float*)d_in[7];
  const float* clsW  = (const float*)d_in[8];
  const float* clsb  = (const float*)d_in[9];
  float* out = (float*)d_out;

  const size_t n_f32 = (size_t)ETOT * 2 + NN * 2 + NN * 2 + HC + HC + 1;
  const size_t need_fast =
      sizeof(unsigned short) * ((size_t)GNF * GK + (size_t)NN * GK + (size_t)NN * GNF) +
      sizeof(float) * n_f32;                     // ~258 MB
  bool fast = ws_size >= need_fast;

  unsigned short* Wt = (unsigned short*)d_ws;             // 3072*768 (Wl|Wr)
  unsigned short* embb = Wt + (size_t)GNF * GK;           // fast only: NN*768
  unsigned short* x = fast ? embb + (size_t)NN * GK
                           : embb;                        // NN*3072
  float* fregion = (float*)(x + (size_t)NN * GNF);
  float* wbuf   = fregion;                       // ETOT*2
  float* denom  = wbuf + (size_t)ETOT * 2;       // NN*2
  float* c      = denom + (size_t)NN * 2;        // NN*2
  float* t      = c + (size_t)NN * 2;            // HC
  float* pooled = t + HC;                        // HC
  float* cnt    = pooled + HC;                   // 1
  int zero_count = (int)(NN * 2 + NN * 2 + HC + HC + 1);

  // 0) zero accumulators (denom..cnt contiguous)
  zero_f32<<<128, 256, 0, stream>>>(denom, zero_count);

  // 0b) W -> Wt (bf16, transposed): rows 0..1535 = W_l cols, 1536..3071 = W_r
  dim3 tgrid(HC / 32, GK / 32);
  transpose_bf16<<<tgrid, 256, 0, stream>>>(W_l, Wt);
  transpose_bf16<<<tgrid, 256, 0, stream>>>(W_r, Wt + (size_t)HC * GK);

  // 1) x = emb @ [W_l | W_r]   (fused bf16 MFMA, bf16 out)
  if (fast) {
    cvt_f32_bf16<<<2048, 256, 0, stream>>>(emb, embb, NN * GK / 8);
    gemm_mfma2<<<(NN / 256) * (GNF / 256), 512, 0, stream>>>(embb, Wt, x);
  } else {
    gemm_mfma<<<(NN / 128) * (GNF / 128), 256, 0, stream>>>(emb, Wt, x);
  }

  // 2) edge logits + denom
  edge_logits<<<(ETOT + 3) / 4, 256, 0, stream>>>(x, edges, att, wbuf, denom);

  // 2b) mask count (independent)
  count_mask<<<32, 256, 0, stream>>>(mask, cnt);

  // 3) alpha -> c[src,h]
  alpha_scatter<<<(ETOT + 255) / 256, 256, 0, stream>>>(edges, mask, wbuf, denom, c);

  // 4) t = c^T @ emb  [2,768]
  if (fast) {
    c_emb_gemv_b<<<NN / 128, 256, 0, stream>>>(embb, c, t);
  } else {
    c_emb_gemv<<<NN / 128, 256, 0, stream>>>(emb, c, t);
  }

  // 5) pooled = t @ W_l (per-head slice)
  pooled_gemv<<<HC / 256, 256, 0, stream>>>(t, W_l, pooled);

  // 6) finalize
  finalize<<<1, 64, 0, stream>>>(pooled, cnt, gbias, clsW, clsb, labels, out);
}

// Round 10
// 505.464 us; speedup vs baseline: 1.1968x; 1.1968x over previous
//
#include <hip/hip_runtime.h>
#include <hip/hip_bf16.h>

// Problem dims (fixed by reference setup_inputs)
#define NN 32768
#define HH 768
#define HEADS 2
#define EE 131072
#define HC (HEADS*HH)      // 1536
#define ETOT (EE + NN)     // 163840 (edges + self loops)
#define NEG_SLOPE 0.2f
#define GK 768             // GEMM K
#define GNF 3072           // fused GEMM N ([W_l | W_r] cols)

typedef __bf16 bf16x8 __attribute__((ext_vector_type(8)));
typedef float f32x4 __attribute__((ext_vector_type(4)));
typedef unsigned short u16x8 __attribute__((ext_vector_type(8)));

// bf16 <-> f32 helpers (RNE, finite data only)
__device__ __forceinline__ float b2f(unsigned short u) {
  union { float f; unsigned int i; } v; v.i = ((unsigned int)u) << 16; return v.f;
}
__device__ __forceinline__ unsigned short f2b(float f) {
  unsigned int x = __float_as_uint(f);
  x += 0x7fff + ((x >> 16) & 1);
  return (unsigned short)(x >> 16);
}
__device__ __forceinline__ void glds16(const unsigned short* g, unsigned short* l) {
  __builtin_amdgcn_global_load_lds(
      (const __attribute__((address_space(1))) unsigned int*)g,
      (__attribute__((address_space(3))) unsigned int*)l, 16, 0, 0);
}

// ---------------- zero a float region ----------------
__global__ __launch_bounds__(256) void zero_f32(float* __restrict__ p, int n) {
  int i = blockIdx.x * blockDim.x + threadIdx.x;
  int st = gridDim.x * blockDim.x;
  for (; i < n; i += st) p[i] = 0.f;
}

// ---------------- emb f32 -> bf16 (vectorized, 8 elems/thread/iter) ----------
__global__ __launch_bounds__(256) void cvt_f32_bf16(
    const float* __restrict__ in, unsigned short* __restrict__ out, int n8) {
  int i = blockIdx.x * blockDim.x + threadIdx.x;
  int st = gridDim.x * blockDim.x;
  for (; i < n8; i += st) {
    float4 a = *(const float4*)(in + (size_t)i * 8);
    float4 b = *(const float4*)(in + (size_t)i * 8 + 4);
    u16x8 w;
    w[0] = f2b(a.x); w[1] = f2b(a.y); w[2] = f2b(a.z); w[3] = f2b(a.w);
    w[4] = f2b(b.x); w[5] = f2b(b.y); w[6] = f2b(b.z); w[7] = f2b(b.w);
    *(u16x8*)(out + (size_t)i * 8) = w;
  }
}

// ------------- W[768][1536] f32 -> Wt[1536][768] bf16 (transpose+convert) ----
__global__ __launch_bounds__(256) void transpose_bf16(
    const float* __restrict__ W, unsigned short* __restrict__ Wt) {
  __shared__ float tile[32][33];
  int n0 = blockIdx.x * 32, k0 = blockIdx.y * 32;
  int tx = threadIdx.x & 31, ty = threadIdx.x >> 5;  // 32 x 8
#pragma unroll
  for (int s = 0; s < 4; ++s)
    tile[ty + s * 8][tx] = W[(size_t)(k0 + ty + s * 8) * HC + n0 + tx];
  __syncthreads();
#pragma unroll
  for (int s = 0; s < 4; ++s)
    Wt[(size_t)(n0 + ty + s * 8) * GK + k0 + tx] = f2b(tile[tx][ty + s * 8]);
}

// ======== GEMM: 256x256, 8 waves, R6 2-barrier 8-phase schedule ==============
// x[32768][3072] (fp8 e4m3) = Ab * Bt^T.  BK=64; 4 phases/K-tile; per phase:
//   stage -> ds_reads -> [VM(8) on p1/p3] -> barrier -> setprio MFMA -> barrier
// (empirically fastest of 3 schedule variants: 281 vs 325/344 us).
// Operand-swapped MFMA (D rows = n, cols = m; validated R9) -> lane holds 4
// consecutive n per frag -> packed 4B fp8 stores via v_cvt_pk_fp8_f32.
__global__ __launch_bounds__(512, 2) void gemm_mfma2(
    const unsigned short* __restrict__ Ab, const unsigned short* __restrict__ Bt,
    unsigned char* __restrict__ X) {
  __shared__ unsigned short Abuf[2][16384];  // [buf][rhalf*8192+kh*4096+q*1024+row*8]
  __shared__ unsigned short Bbuf[2][16384];
  int tid = threadIdx.x, lane = tid & 63, w = tid >> 6;
  int wr = w >> 2, wc = w & 3;          // wave grid 2M x 4N
  int ql = lane >> 4, ml = lane & 15;
  // XCD-bijective walk: 1536 = 8 XCD x (16 m x 12 n), n fastest
  int b = blockIdx.x;
  int xcd = b & 7, loc = b >> 3;
  int m_blk = xcd * 16 + loc / 12, n_blk = loc % 12;
  int m0 = m_blk * 256, n0 = n_blk * 256;

  // staging mapping: thread covers chunk (q=w>>1, row=(w&1)*64+lane)
  int qd = w >> 1, rloc = (w & 1) * 64 + lane;
  const unsigned short* sA0 = Ab + (size_t)(m0 + rloc) * GK + qd * 8;
  const unsigned short* sA1 = Ab + (size_t)(m0 + 128 + rloc) * GK + qd * 8;
  const unsigned short* sB0 = Bt + (size_t)(n0 + rloc) * GK + qd * 8;
  const unsigned short* sB1 = Bt + (size_t)(n0 + 128 + rloc) * GK + qd * 8;
  int lof0 = qd * 1024 + rloc * 8;
  // read bases
  int A0 = ((wr * 8 + ql) * 128 + ml) * 8;
  int B0 = (((wc >> 1) * 8 + ql) * 128 + (wc & 1) * 64 + ml) * 8;

  f32x4 acc[8][4] = {};
  bf16x8 a[4], bb[4];

#define SA(s_, kt_, kh_) {                                              \
    glds16(sA0 + (kt_)*64 + (kh_)*32, &Abuf[s_][(kh_)*4096 + lof0]);    \
    glds16(sA1 + (kt_)*64 + (kh_)*32, &Abuf[s_][(kh_)*4096 + lof0 + 8192]); }
#define SB(s_, kt_, kh_) {                                              \
    glds16(sB0 + (kt_)*64 + (kh_)*32, &Bbuf[s_][(kh_)*4096 + lof0]);    \
    glds16(sB1 + (kt_)*64 + (kh_)*32, &Bbuf[s_][(kh_)*4096 + lof0 + 8192]); }
#define LDA_(mh_, kh_, s_) { _Pragma("unroll") for (int i = 0; i < 4; ++i) \
    a[i] = *(const bf16x8*)&Abuf[s_][A0 + (kh_)*4096 + ((mh_)*4 + i)*128]; }
#define LDB_(kh_, s_) { _Pragma("unroll") for (int j = 0; j < 4; ++j) \
    bb[j] = *(const bf16x8*)&Bbuf[s_][B0 + (kh_)*4096 + j*128]; }
// operand-swapped: D rows = n (frag j), cols = m (frag mh*4+i)  [validated R9]
#define MM(mh_) { _Pragma("unroll") for (int i = 0; i < 4; ++i) {       \
    _Pragma("unroll") for (int j = 0; j < 4; ++j)                       \
      acc[(mh_)*4+i][j] = __builtin_amdgcn_mfma_f32_16x16x32_bf16(      \
          bb[j], a[i], acc[(mh_)*4+i][j], 0, 0, 0); } }
#define SBR __builtin_amdgcn_sched_barrier(0)
#define BARRIER { SBR; __builtin_amdgcn_s_barrier(); SBR; }
#define VM(n_) { asm volatile("s_waitcnt vmcnt(" #n_ ")" ::: "memory"); }
#define PMM(mh_) { __builtin_amdgcn_s_setprio(1); MM(mh_); __builtin_amdgcn_s_setprio(0); }

  // prologue: T0 kh0, T0 kh1, T1 kh0 (12 loads); land T0 kh0
  SA(0, 0, 0); SB(0, 0, 0);
  SA(0, 0, 1); SB(0, 0, 1);
  SA(1, 1, 0); SB(1, 1, 0);
  VM(8); BARRIER;

#pragma unroll 1
  for (int kt = 0; kt < 10; ++kt) {
    int s = kt & 1, sn = s ^ 1;
    // p0: stage T(kt+1) kh1 A; read T(kt) kh0
    SA(sn, kt + 1, 1);
    LDB_(0, s); LDA_(0, 0, s);
    BARRIER; PMM(0); BARRIER;
    // p1: stage T(kt+1) kh1 B; VM lands T(kt) kh1 for p2
    SB(sn, kt + 1, 1);
    LDA_(1, 0, s);
    VM(8); BARRIER; PMM(1); BARRIER;
    // p2: stage T(kt+2) kh0 A; read T(kt) kh1
    SA(s, kt + 2, 0);
    LDB_(1, s); LDA_(0, 1, s);
    BARRIER; PMM(0); BARRIER;
    // p3: stage T(kt+2) kh0 B; VM lands T(kt+1) kh0 for next p0
    SB(s, kt + 2, 0);
    LDA_(1, 1, s);
    VM(8); BARRIER; PMM(1); BARRIER;
  }
  // kt = 10 (s=0): only T11 kh1 stage remains
  SA(1, 11, 1); LDB_(0, 0); LDA_(0, 0, 0); BARRIER; PMM(0); BARRIER;
  SB(1, 11, 1); LDA_(1, 0, 0); VM(8); BARRIER; PMM(1); BARRIER;
  LDB_(1, 0); LDA_(0, 1, 0); BARRIER; PMM(0); BARRIER;
  LDA_(1, 1, 0); VM(4); BARRIER; PMM(1); BARRIER;
  // kt = 11 (s=1): no stages
  LDB_(0, 1); LDA_(0, 0, 1); BARRIER; PMM(0); BARRIER;
  LDA_(1, 0, 1); VM(0); BARRIER; PMM(1); BARRIER;
  LDB_(1, 1); LDA_(0, 1, 1); BARRIER; PMM(0); BARRIER;
  LDA_(1, 1, 1); BARRIER; PMM(1);

  // epilogue: lane holds n = n0+wc*64+j*16+ql*4+{0..3} (consecutive) per frag,
  // m = m0 + wr*128 + mf*16 + ml -> pack 4 fp8 into one 4B store
#pragma unroll
  for (int mf = 0; mf < 8; ++mf) {
    int m = m0 + wr * 128 + mf * 16 + ml;
    unsigned char* Cp = X + (size_t)m * GNF + n0 + wc * 64 + ql * 4;
#pragma unroll
    for (int j = 0; j < 4; ++j) {
      int pk = 0;
      pk = __builtin_amdgcn_cvt_pk_fp8_f32(acc[mf][j][0], acc[mf][j][1], pk, false);
      pk = __builtin_amdgcn_cvt_pk_fp8_f32(acc[mf][j][2], acc[mf][j][3], pk, true);
      *(int*)(Cp + j * 16) = pk;
    }
  }
#undef SA
#undef SB
#undef LDA_
#undef LDB_
#undef MM
#undef BARRIER
#undef VM
#undef PMM
}

// ------------- edge logits (fp8 x): wave/edge, w = exp(logit), denom scatter -
// x row n = [x_l(n) 1536 | x_r(n) 1536] fp8 e4m3, stride 3072 bytes.
__global__ __launch_bounds__(256) void edge_logits(
    const unsigned char* __restrict__ x,
    const int* __restrict__ edges, const float* __restrict__ att,
    float* __restrict__ wbuf, float* __restrict__ denom) {
  int wave = (int)((blockIdx.x * blockDim.x + threadIdx.x) >> 6);
  int lane = threadIdx.x & 63;
  if (wave >= ETOT) return;
  int src, dst;
  if (wave < EE) {
    src = edges[wave];
    dst = edges[EE + wave];
  } else {
    src = dst = wave - EE;
  }
  const unsigned char* pl = x + (size_t)src * GNF;          // x_l[src]
  const unsigned char* pr = x + (size_t)dst * GNF + HC;     // x_r[dst]
#pragma unroll
  for (int h = 0; h < HEADS; ++h) {
    float s = 0.f;
    const unsigned char* phl = pl + h * HH;
    const unsigned char* phr = pr + h * HH;
    const float* pa = att + h * HH;
#pragma unroll
    for (int it = 0; it < 3; ++it) {
      int d = (it * 64 + lane) * 4;
      int al = *(const int*)(phl + d);
      int ar = *(const int*)(phr + d);
      float4 w = *(const float4*)(pa + d);
      float x0 = __builtin_amdgcn_cvt_f32_fp8(al, 0) + __builtin_amdgcn_cvt_f32_fp8(ar, 0);
      float x1 = __builtin_amdgcn_cvt_f32_fp8(al, 1) + __builtin_amdgcn_cvt_f32_fp8(ar, 1);
      float x2 = __builtin_amdgcn_cvt_f32_fp8(al, 2) + __builtin_amdgcn_cvt_f32_fp8(ar, 2);
      float x3 = __builtin_amdgcn_cvt_f32_fp8(al, 3) + __builtin_amdgcn_cvt_f32_fp8(ar, 3);
      x0 = x0 >= 0.f ? x0 : NEG_SLOPE * x0;
      x1 = x1 >= 0.f ? x1 : NEG_SLOPE * x1;
      x2 = x2 >= 0.f ? x2 : NEG_SLOPE * x2;
      x3 = x3 >= 0.f ? x3 : NEG_SLOPE * x3;
      s += x0 * w.x + x1 * w.y + x2 * w.z + x3 * w.w;
    }
#pragma unroll
    for (int off = 32; off; off >>= 1) s += __shfl_down(s, off);
    if (lane == 0) {
      float wv = expf(s);
      wbuf[(size_t)wave * 2 + h] = wv;
      atomicAdd(&denom[(size_t)dst * 2 + h], wv);
    }
  }
}

// ------------- alpha -> per-source scalar coefficients (masked by dst) -------
__global__ __launch_bounds__(256) void alpha_scatter(
    const int* __restrict__ edges, const int* __restrict__ mask,
    const float* __restrict__ wbuf, const float* __restrict__ denom,
    float* __restrict__ c) {
  int e = blockIdx.x * blockDim.x + threadIdx.x;
  if (e >= ETOT) return;
  int src, dst;
  if (e < EE) {
    src = edges[e];
    dst = edges[EE + e];
  } else {
    src = dst = e - EE;
  }
  if (mask[dst]) {
    atomicAdd(&c[(size_t)src * 2 + 0], wbuf[(size_t)e * 2 + 0] / denom[(size_t)dst * 2 + 0]);
    atomicAdd(&c[(size_t)src * 2 + 1], wbuf[(size_t)e * 2 + 1] / denom[(size_t)dst * 2 + 1]);
  }
}

// ------------- count masked nodes (float; exact below 2^24) ------------------
__global__ __launch_bounds__(256) void count_mask(
    const int* __restrict__ mask, float* __restrict__ cnt) {
  int t = blockIdx.x * blockDim.x + threadIdx.x;
  int stride = gridDim.x * blockDim.x;
  float local = 0.f;
  for (int i = t; i < NN; i += stride) local += (mask[i] != 0) ? 1.f : 0.f;
#pragma unroll
  for (int off = 32; off; off >>= 1) local += __shfl_down(local, off);
  if ((threadIdx.x & 63) == 0 && local != 0.f) atomicAdd(cnt, local);
}

// ------------- t[h,k] = sum_n c[n,h] * emb[n,k]  (bf16 emb) ------------------
__global__ __launch_bounds__(256) void c_emb_gemv_b(
    const unsigned short* __restrict__ embb, const float* __restrict__ c,
    float* __restrict__ t) {
  int tid = threadIdx.x;   // 256
  int b = blockIdx.x;      // 256 blocks x 128 rows
  float a0[3] = {}, a1[3] = {};
  int n0 = b * 128;
  for (int r = 0; r < 128; ++r) {
    int n = n0 + r;
    float c0 = c[(size_t)n * 2 + 0];
    float c1 = c[(size_t)n * 2 + 1];
    const unsigned short* row = embb + (size_t)n * HH;
#pragma unroll
    for (int k = 0; k < 3; ++k) {
      float v = b2f(row[tid + k * 256]);
      a0[k] += c0 * v;
      a1[k] += c1 * v;
    }
  }
#pragma unroll
  for (int k = 0; k < 3; ++k) {
    atomicAdd(&t[tid + k * 256], a0[k]);
    atomicAdd(&t[HH + tid + k * 256], a1[k]);
  }
}

// ------------- pooled[h*768+d] = sum_k t[h,k] * W_l[k, h*768+d] --------------
__global__ __launch_bounds__(256) void pooled_gemv(
    const float* __restrict__ t, const float* __restrict__ W_l,
    float* __restrict__ pooled) {
  int idx = blockIdx.x * blockDim.x + threadIdx.x;  // 6*256 = 1536
  if (idx >= HC) return;
  int h = idx / HH;
  float s = 0.f;
  const float* tp = t + (size_t)h * HH;
  const float* wp = W_l + idx;
  for (int k = 0; k < HH; ++k) s += tp[k] * wp[(size_t)k * HC];
  pooled[idx] = s;
}

// ------------- finalize: psy -> classifier -> loss/pred/acc ------------------
__global__ __launch_bounds__(64) void finalize(
    const float* __restrict__ pooled, const float* __restrict__ cntp,
    const float* __restrict__ bias, const float* __restrict__ clsW,
    const float* __restrict__ clsb, const int* __restrict__ labels,
    float* __restrict__ out) {
  int lane = threadIdx.x;  // 64
  float cnt = *cntp;
  float inv = 1.f / (cnt + 1e-8f);
  __shared__ float lin[8];
  for (int lo = 0; lo < 8; ++lo) {
    int l = lo >> 1, o = lo & 1;
    float s = 0.f;
    for (int d = lane; d < HH; d += 64) {
      float psy = (0.5f * (pooled[d] + pooled[HH + d]) + cnt * bias[d]) * inv;
      s += psy * clsW[(size_t)l * HH * 2 + (size_t)d * 2 + o];
    }
#pragma unroll
    for (int off = 32; off; off >>= 1) s += __shfl_down(s, off);
    if (lane == 0) lin[lo] = s + clsb[lo];
  }
  __syncthreads();
  if (lane == 0) {
    float loss = 0.f, accv = 0.f;
    for (int l = 0; l < 4; ++l) {
      float a = lin[l * 2], bb = lin[l * 2 + 1];
      float m = fmaxf(a, bb);
      float ea = expf(a - m), eb = expf(bb - m);
      float inv2 = 1.f / (ea + eb);
      float p0 = ea * inv2, p1 = eb * inv2;
      // reference applies log_softmax to the PROBS (double-softmax quirk)
      float m2 = fmaxf(p0, p1);
      float lse = m2 + logf(expf(p0 - m2) + expf(p1 - m2));
      float lp0 = p0 - lse, lp1 = p1 - lse;
      int lab = labels[l];
      loss -= (lab == 1) ? lp1 : lp0;
      int pred = (p1 > p0) ? 1 : 0;  // argmax: first index on tie
      out[1 + l] = (float)pred;
      accv += (pred == lab) ? 1.f : 0.f;
    }
    out[0] = loss;
    out[5] = accv;
  }
}

// ---------------------------------------------------------------------------
extern "C" void kernel_launch(void* const* d_in, const int* in_sizes, int n_in,
                              void* d_out, int out_size, void* d_ws, size_t ws_size,
                              hipStream_t stream) {
  const float* emb   = (const float*)d_in[0];
  const int*   mask  = (const int*)d_in[1];
  const int*   edges = (const int*)d_in[2];
  const int*   labels= (const int*)d_in[3];
  const float* W_l   = (const float*)d_in[4];
  const float* W_r   = (const float*)d_in[5];
  const float* att   = (const float*)d_in[6];
  const float* gbias = (const float*)d_in[7];
  const float* clsW  = (const float*)d_in[8];
  const float* clsb  = (const float*)d_in[9];
  float* out = (float*)d_out;

  // workspace (~157 MB; ws proven >= 258 MB by rounds 5-9):
  unsigned short* Wt   = (unsigned short*)d_ws;           // 3072*768 bf16
  unsigned short* embb = Wt + (size_t)GNF * GK;           // NN*768 bf16
  unsigned char*  x    = (unsigned char*)(embb + (size_t)NN * GK);  // NN*3072 fp8
  float* fregion = (float*)(x + (size_t)NN * GNF);
  float* wbuf   = fregion;                       // ETOT*2
  float* denom  = wbuf + (size_t)ETOT * 2;       // NN*2
  float* c      = denom + (size_t)NN * 2;        // NN*2
  float* t      = c + (size_t)NN * 2;            // HC
  float* pooled = t + HC;                        // HC
  float* cnt    = pooled + HC;                   // 1
  int zero_count = (int)(NN * 2 + NN * 2 + HC + HC + 1);

  // 0) zero accumulators (denom..cnt contiguous)
  zero_f32<<<128, 256, 0, stream>>>(denom, zero_count);

  // 0b) W -> Wt (bf16, transposed): rows 0..1535 = W_l cols, 1536..3071 = W_r
  dim3 tgrid(HC / 32, GK / 32);
  transpose_bf16<<<tgrid, 256, 0, stream>>>(W_l, Wt);
  transpose_bf16<<<tgrid, 256, 0, stream>>>(W_r, Wt + (size_t)HC * GK);

  // 1) x = emb @ [W_l | W_r]   (bf16 MFMA, fp8 out)
  cvt_f32_bf16<<<2048, 256, 0, stream>>>(emb, embb, NN * GK / 8);
  gemm_mfma2<<<(NN / 256) * (GNF / 256), 512, 0, stream>>>(embb, Wt, x);

  // 2) edge logits + denom
  edge_logits<<<(ETOT + 3) / 4, 256, 0, stream>>>(x, edges, att, wbuf, denom);

  // 2b) mask count (independent)
  count_mask<<<32, 256, 0, stream>>>(mask, cnt);

  // 3) alpha -> c[src,h]
  alpha_scatter<<<(ETOT + 255) / 256, 256, 0, stream>>>(edges, mask, wbuf, denom, c);

  // 4) t = c^T @ emb  [2,768]  (pooled path stays high-precision)
  c_emb_gemv_b<<<NN / 128, 256, 0, stream>>>(embb, c, t);

  // 5) pooled = t @ W_l (per-head slice, exact fp32)
  pooled_gemv<<<HC / 256, 256, 0, stream>>>(t, W_l, pooled);

  // 6) finalize
  finalize<<<1, 64, 0, stream>>>(pooled, cnt, gbias, clsW, clsb, labels, out);
}

// Round 11
// 432.114 us; speedup vs baseline: 1.4000x; 1.1697x over previous
//
#include <hip/hip_runtime.h>
#include <hip/hip_bf16.h>

// Problem dims (fixed by reference setup_inputs)
#define NN 32768
#define HH 768
#define HEADS 2
#define EE 131072
#define HC (HEADS*HH)      // 1536
#define ETOT (EE + NN)     // 163840 (edges + self loops)
#define NEG_SLOPE 0.2f
#define GK 768             // GEMM K
#define GNF 3072           // fused GEMM N ([W_l | W_r] cols)

typedef float f32x16 __attribute__((ext_vector_type(16)));
typedef int i32x8 __attribute__((ext_vector_type(8)));
typedef unsigned short u16x8 __attribute__((ext_vector_type(8)));

// bf16 <-> f32 helpers (RNE, finite data only)
__device__ __forceinline__ float b2f(unsigned short u) {
  union { float f; unsigned int i; } v; v.i = ((unsigned int)u) << 16; return v.f;
}
__device__ __forceinline__ unsigned short f2b(float f) {
  unsigned int x = __float_as_uint(f);
  x += 0x7fff + ((x >> 16) & 1);
  return (unsigned short)(x >> 16);
}
__device__ __forceinline__ void glds16b(const unsigned char* g, unsigned char* l) {
  __builtin_amdgcn_global_load_lds(
      (const __attribute__((address_space(1))) unsigned int*)g,
      (__attribute__((address_space(3))) unsigned int*)l, 16, 0, 0);
}

// ---------------- zero a float region ----------------
__global__ __launch_bounds__(256) void zero_f32(float* __restrict__ p, int n) {
  int i = blockIdx.x * blockDim.x + threadIdx.x;
  int st = gridDim.x * blockDim.x;
  for (; i < n; i += st) p[i] = 0.f;
}

// -------- emb f32 -> {bf16, fp8 e4m3} in one pass (8 elems/thread/iter) ------
__global__ __launch_bounds__(256) void cvt_emb(
    const float* __restrict__ in, unsigned short* __restrict__ outb,
    unsigned char* __restrict__ out8, int n8) {
  int i = blockIdx.x * blockDim.x + threadIdx.x;
  int st = gridDim.x * blockDim.x;
  for (; i < n8; i += st) {
    float4 a = *(const float4*)(in + (size_t)i * 8);
    float4 b = *(const float4*)(in + (size_t)i * 8 + 4);
    u16x8 w;
    w[0] = f2b(a.x); w[1] = f2b(a.y); w[2] = f2b(a.z); w[3] = f2b(a.w);
    w[4] = f2b(b.x); w[5] = f2b(b.y); w[6] = f2b(b.z); w[7] = f2b(b.w);
    *(u16x8*)(outb + (size_t)i * 8) = w;
    int pk0 = 0, pk1 = 0;
    pk0 = __builtin_amdgcn_cvt_pk_fp8_f32(a.x, a.y, pk0, false);
    pk0 = __builtin_amdgcn_cvt_pk_fp8_f32(a.z, a.w, pk0, true);
    pk1 = __builtin_amdgcn_cvt_pk_fp8_f32(b.x, b.y, pk1, false);
    pk1 = __builtin_amdgcn_cvt_pk_fp8_f32(b.z, b.w, pk1, true);
    int2 pk; pk.x = pk0; pk.y = pk1;
    *(int2*)(out8 + (size_t)i * 8) = pk;
  }
}

// ------- W[768][1536] f32 -> Wt8[1536][768] fp8 (transpose+convert) ----------
__global__ __launch_bounds__(256) void transpose_fp8(
    const float* __restrict__ W, unsigned char* __restrict__ Wt) {
  __shared__ float tile[32][33];
  int n0 = blockIdx.x * 32, k0 = blockIdx.y * 32;
  int tx = threadIdx.x & 31, ty = threadIdx.x >> 5;  // 32 x 8
#pragma unroll
  for (int s = 0; s < 4; ++s)
    tile[ty + s * 8][tx] = W[(size_t)(k0 + ty + s * 8) * HC + n0 + tx];
  __syncthreads();
#pragma unroll
  for (int s = 0; s < 4; ++s) {
    int pk = __builtin_amdgcn_cvt_pk_fp8_f32(tile[tx][ty + s * 8], 0.f, 0, false);
    Wt[(size_t)(n0 + ty + s * 8) * GK + k0 + tx] = (unsigned char)(pk & 0xff);
  }
}

// ======== GEMM (MX-fp8): x[32768][3072] fp8 = emb8 @ Wt8^T ===================
// 128x128 tile, BK=64, 4 waves (2x2, wave tile 64x64), mfma_scale 32x32x64
// f8f6f4 (fmt fp8/fp8, scale bytes 0x7F = 1.0).  3 rotating LDS buffers
// (48 KB -> 3 blocks/CU = 3 waves/SIMD), R6-proven counted-vmcnt schedule:
// stage T+2 after barrier, VM(4)+lgkm(0) before it.  LDS layout [q 0..3]
// [row 0..127][16B] (k-chunk-major): frag read = 2x b128/lane, floor-aliased.
// Operand-swapped MFMA (D rows = n): lane holds 4 consecutive n per reg-quad
// -> packed 4B fp8 stores (cvt_pk_fp8).
__global__ __launch_bounds__(256, 3) void gemm_fp8(
    const unsigned char* __restrict__ A8, const unsigned char* __restrict__ B8,
    unsigned char* __restrict__ X) {
  __shared__ unsigned char Abuf[3][8192];
  __shared__ unsigned char Bbuf[3][8192];
  int tid = threadIdx.x, lane = tid & 63, wv = tid >> 6;
  int wvr = wv >> 1, wvc = wv & 1;
  // XCD + L2-aware walk (6144 blocks, bijective; R6-proven)
  int b = blockIdx.x;
  int xcd = b & 7, local = b >> 3;
  int nh = local / 384, rem = local % 384;
  int mgrp = rem / 96, inner = rem % 96;
  int m_blk = xcd * 32 + mgrp * 8 + inner / 12;
  int n_blk = nh * 12 + inner % 12;
  int m0 = m_blk * 128, n0 = n_blk * 128;

  // staging: thread covers 16B chunks tid and tid+256; chunk = q*128 + row
  int q0 = tid >> 7, r0 = tid & 127;   // q0 in 0..1
  const unsigned char* sA0 = A8 + (size_t)(m0 + r0) * GK + q0 * 16;
  const unsigned char* sA1 = A8 + (size_t)(m0 + r0) * GK + (q0 + 2) * 16;
  const unsigned char* sB0 = B8 + (size_t)(n0 + r0) * GK + q0 * 16;
  const unsigned char* sB1 = B8 + (size_t)(n0 + r0) * GK + (q0 + 2) * 16;
  int lof0 = tid * 16, lof1 = (tid + 256) * 16;

  // read bases: lane reads rows (l&31) of its 32-group, k-half (l>>5)
  int arow = wvr * 64 + (lane & 31);
  int brow = wvc * 64 + (lane & 31);
  int qb = (lane >> 5) * 2;

  f32x16 acc[2][2] = {};

#define STG(s_, kt_) {                              \
    glds16b(sA0 + (kt_)*64, &Abuf[s_][lof0]);       \
    glds16b(sA1 + (kt_)*64, &Abuf[s_][lof1]);       \
    glds16b(sB0 + (kt_)*64, &Bbuf[s_][lof0]);       \
    glds16b(sB1 + (kt_)*64, &Bbuf[s_][lof1]); }

  // prologue: tiles 0,1 -> bufs 0,1 (8 loads in flight)
  STG(0, 0); STG(1, 1);

  const int NT = GK / 64;  // 12
  int cur = 0;
#pragma unroll 1
  for (int t = 0; t < NT; ++t) {
    if (t + 1 < NT) {
      asm volatile("s_waitcnt vmcnt(4) lgkmcnt(0)" ::: "memory");
    } else {
      asm volatile("s_waitcnt vmcnt(0) lgkmcnt(0)" ::: "memory");
    }
    __builtin_amdgcn_sched_barrier(0);
    __builtin_amdgcn_s_barrier();
    __builtin_amdgcn_sched_barrier(0);
    if (t + 2 < NT) { int nb = (t + 2) % 3; STG(nb, t + 2); }
    i32x8 af[2], bf[2];
#pragma unroll
    for (int mg = 0; mg < 2; ++mg) {
      int4 lo = *(const int4*)&Abuf[cur][(qb * 128 + arow + mg * 32) * 16];
      int4 hi = *(const int4*)&Abuf[cur][((qb + 1) * 128 + arow + mg * 32) * 16];
      af[mg][0] = lo.x; af[mg][1] = lo.y; af[mg][2] = lo.z; af[mg][3] = lo.w;
      af[mg][4] = hi.x; af[mg][5] = hi.y; af[mg][6] = hi.z; af[mg][7] = hi.w;
    }
#pragma unroll
    for (int ng = 0; ng < 2; ++ng) {
      int4 lo = *(const int4*)&Bbuf[cur][(qb * 128 + brow + ng * 32) * 16];
      int4 hi = *(const int4*)&Bbuf[cur][((qb + 1) * 128 + brow + ng * 32) * 16];
      bf[ng][0] = lo.x; bf[ng][1] = lo.y; bf[ng][2] = lo.z; bf[ng][3] = lo.w;
      bf[ng][4] = hi.x; bf[ng][5] = hi.y; bf[ng][6] = hi.z; bf[ng][7] = hi.w;
    }
    __builtin_amdgcn_s_setprio(1);
#pragma unroll
    for (int mg = 0; mg < 2; ++mg)
#pragma unroll
      for (int ng = 0; ng < 2; ++ng)
        acc[mg][ng] = __builtin_amdgcn_mfma_scale_f32_32x32x64_f8f6f4(
            bf[ng], af[mg], acc[mg][ng], 0, 0,  // fmt A=fp8, B=fp8 (swapped)
            0, 0x7F7F7F7F, 0, 0x7F7F7F7F);      // scales = 1.0 (E8M0 127)
    __builtin_amdgcn_s_setprio(0);
    cur = cur + 1; if (cur == 3) cur = 0;
  }

  // epilogue (swapped 32x32 D layout: col=m=lane&31, row=n=(reg&3)+8*(reg>>2)
  // +4*(lane>>5)): per reg-quad rq, 4 consecutive n -> one 4B fp8 store
#pragma unroll
  for (int mg = 0; mg < 2; ++mg) {
    int m = m0 + wvr * 64 + mg * 32 + (lane & 31);
#pragma unroll
    for (int ng = 0; ng < 2; ++ng) {
      unsigned char* Cp = X + (size_t)m * GNF + n0 + wvc * 64 + ng * 32 + (lane >> 5) * 4;
#pragma unroll
      for (int rq = 0; rq < 4; ++rq) {
        int pk = 0;
        pk = __builtin_amdgcn_cvt_pk_fp8_f32(acc[mg][ng][rq * 4 + 0],
                                             acc[mg][ng][rq * 4 + 1], pk, false);
        pk = __builtin_amdgcn_cvt_pk_fp8_f32(acc[mg][ng][rq * 4 + 2],
                                             acc[mg][ng][rq * 4 + 3], pk, true);
        *(int*)(Cp + rq * 8) = pk;
      }
    }
  }
#undef STG
}

// ------------- edge logits (fp8 x): wave/edge, w = exp(logit), denom scatter -
// x row n = [x_l(n) 1536 | x_r(n) 1536] fp8 e4m3, stride 3072 bytes.
__global__ __launch_bounds__(256) void edge_logits(
    const unsigned char* __restrict__ x,
    const int* __restrict__ edges, const float* __restrict__ att,
    float* __restrict__ wbuf, float* __restrict__ denom) {
  int wave = (int)((blockIdx.x * blockDim.x + threadIdx.x) >> 6);
  int lane = threadIdx.x & 63;
  if (wave >= ETOT) return;
  int src, dst;
  if (wave < EE) {
    src = edges[wave];
    dst = edges[EE + wave];
  } else {
    src = dst = wave - EE;
  }
  const unsigned char* pl = x + (size_t)src * GNF;          // x_l[src]
  const unsigned char* pr = x + (size_t)dst * GNF + HC;     // x_r[dst]
#pragma unroll
  for (int h = 0; h < HEADS; ++h) {
    float s = 0.f;
    const unsigned char* phl = pl + h * HH;
    const unsigned char* phr = pr + h * HH;
    const float* pa = att + h * HH;
#pragma unroll
    for (int it = 0; it < 3; ++it) {
      int d = (it * 64 + lane) * 4;
      int al = *(const int*)(phl + d);
      int ar = *(const int*)(phr + d);
      float4 w = *(const float4*)(pa + d);
      float x0 = __builtin_amdgcn_cvt_f32_fp8(al, 0) + __builtin_amdgcn_cvt_f32_fp8(ar, 0);
      float x1 = __builtin_amdgcn_cvt_f32_fp8(al, 1) + __builtin_amdgcn_cvt_f32_fp8(ar, 1);
      float x2 = __builtin_amdgcn_cvt_f32_fp8(al, 2) + __builtin_amdgcn_cvt_f32_fp8(ar, 2);
      float x3 = __builtin_amdgcn_cvt_f32_fp8(al, 3) + __builtin_amdgcn_cvt_f32_fp8(ar, 3);
      x0 = x0 >= 0.f ? x0 : NEG_SLOPE * x0;
      x1 = x1 >= 0.f ? x1 : NEG_SLOPE * x1;
      x2 = x2 >= 0.f ? x2 : NEG_SLOPE * x2;
      x3 = x3 >= 0.f ? x3 : NEG_SLOPE * x3;
      s += x0 * w.x + x1 * w.y + x2 * w.z + x3 * w.w;
    }
#pragma unroll
    for (int off = 32; off; off >>= 1) s += __shfl_down(s, off);
    if (lane == 0) {
      float wv = expf(s);
      wbuf[(size_t)wave * 2 + h] = wv;
      atomicAdd(&denom[(size_t)dst * 2 + h], wv);
    }
  }
}

// ------------- alpha -> per-source scalar coefficients (masked by dst) -------
__global__ __launch_bounds__(256) void alpha_scatter(
    const int* __restrict__ edges, const int* __restrict__ mask,
    const float* __restrict__ wbuf, const float* __restrict__ denom,
    float* __restrict__ c) {
  int e = blockIdx.x * blockDim.x + threadIdx.x;
  if (e >= ETOT) return;
  int src, dst;
  if (e < EE) {
    src = edges[e];
    dst = edges[EE + e];
  } else {
    src = dst = e - EE;
  }
  if (mask[dst]) {
    atomicAdd(&c[(size_t)src * 2 + 0], wbuf[(size_t)e * 2 + 0] / denom[(size_t)dst * 2 + 0]);
    atomicAdd(&c[(size_t)src * 2 + 1], wbuf[(size_t)e * 2 + 1] / denom[(size_t)dst * 2 + 1]);
  }
}

// ------------- count masked nodes (float; exact below 2^24) ------------------
__global__ __launch_bounds__(256) void count_mask(
    const int* __restrict__ mask, float* __restrict__ cnt) {
  int t = blockIdx.x * blockDim.x + threadIdx.x;
  int stride = gridDim.x * blockDim.x;
  float local = 0.f;
  for (int i = t; i < NN; i += stride) local += (mask[i] != 0) ? 1.f : 0.f;
#pragma unroll
  for (int off = 32; off; off >>= 1) local += __shfl_down(local, off);
  if ((threadIdx.x & 63) == 0 && local != 0.f) atomicAdd(cnt, local);
}

// ------------- t[h,k] = sum_n c[n,h] * emb[n,k]  (bf16 emb) ------------------
__global__ __launch_bounds__(256) void c_emb_gemv_b(
    const unsigned short* __restrict__ embb, const float* __restrict__ c,
    float* __restrict__ t) {
  int tid = threadIdx.x;   // 256
  int b = blockIdx.x;      // 256 blocks x 128 rows
  float a0[3] = {}, a1[3] = {};
  int n0 = b * 128;
  for (int r = 0; r < 128; ++r) {
    int n = n0 + r;
    float c0 = c[(size_t)n * 2 + 0];
    float c1 = c[(size_t)n * 2 + 1];
    const unsigned short* row = embb + (size_t)n * HH;
#pragma unroll
    for (int k = 0; k < 3; ++k) {
      float v = b2f(row[tid + k * 256]);
      a0[k] += c0 * v;
      a1[k] += c1 * v;
    }
  }
#pragma unroll
  for (int k = 0; k < 3; ++k) {
    atomicAdd(&t[tid + k * 256], a0[k]);
    atomicAdd(&t[HH + tid + k * 256], a1[k]);
  }
}

// ------------- pooled[h*768+d] = sum_k t[h,k] * W_l[k, h*768+d] --------------
__global__ __launch_bounds__(256) void pooled_gemv(
    const float* __restrict__ t, const float* __restrict__ W_l,
    float* __restrict__ pooled) {
  int idx = blockIdx.x * blockDim.x + threadIdx.x;  // 6*256 = 1536
  if (idx >= HC) return;
  int h = idx / HH;
  float s = 0.f;
  const float* tp = t + (size_t)h * HH;
  const float* wp = W_l + idx;
  for (int k = 0; k < HH; ++k) s += tp[k] * wp[(size_t)k * HC];
  pooled[idx] = s;
}

// ------------- finalize: psy -> classifier -> loss/pred/acc ------------------
__global__ __launch_bounds__(64) void finalize(
    const float* __restrict__ pooled, const float* __restrict__ cntp,
    const float* __restrict__ bias, const float* __restrict__ clsW,
    const float* __restrict__ clsb, const int* __restrict__ labels,
    float* __restrict__ out) {
  int lane = threadIdx.x;  // 64
  float cnt = *cntp;
  float inv = 1.f / (cnt + 1e-8f);
  __shared__ float lin[8];
  for (int lo = 0; lo < 8; ++lo) {
    int l = lo >> 1, o = lo & 1;
    float s = 0.f;
    for (int d = lane; d < HH; d += 64) {
      float psy = (0.5f * (pooled[d] + pooled[HH + d]) + cnt * bias[d]) * inv;
      s += psy * clsW[(size_t)l * HH * 2 + (size_t)d * 2 + o];
    }
#pragma unroll
    for (int off = 32; off; off >>= 1) s += __shfl_down(s, off);
    if (lane == 0) lin[lo] = s + clsb[lo];
  }
  __syncthreads();
  if (lane == 0) {
    float loss = 0.f, accv = 0.f;
    for (int l = 0; l < 4; ++l) {
      float a = lin[l * 2], bb = lin[l * 2 + 1];
      float m = fmaxf(a, bb);
      float ea = expf(a - m), eb = expf(bb - m);
      float inv2 = 1.f / (ea + eb);
      float p0 = ea * inv2, p1 = eb * inv2;
      // reference applies log_softmax to the PROBS (double-softmax quirk)
      float m2 = fmaxf(p0, p1);
      float lse = m2 + logf(expf(p0 - m2) + expf(p1 - m2));
      float lp0 = p0 - lse, lp1 = p1 - lse;
      int lab = labels[l];
      loss -= (lab == 1) ? lp1 : lp0;
      int pred = (p1 > p0) ? 1 : 0;  // argmax: first index on tie
      out[1 + l] = (float)pred;
      accv += (pred == lab) ? 1.f : 0.f;
    }
    out[0] = loss;
    out[5] = accv;
  }
}

// ---------------------------------------------------------------------------
extern "C" void kernel_launch(void* const* d_in, const int* in_sizes, int n_in,
                              void* d_out, int out_size, void* d_ws, size_t ws_size,
                              hipStream_t stream) {
  const float* emb   = (const float*)d_in[0];
  const int*   mask  = (const int*)d_in[1];
  const int*   edges = (const int*)d_in[2];
  const int*   labels= (const int*)d_in[3];
  const float* W_l   = (const float*)d_in[4];
  const float* W_r   = (const float*)d_in[5];
  const float* att   = (const float*)d_in[6];
  const float* gbias = (const float*)d_in[7];
  const float* clsW  = (const float*)d_in[8];
  const float* clsb  = (const float*)d_in[9];
  float* out = (float*)d_out;

  // workspace (~180 MB; ws proven >= 258 MB by rounds 5-10):
  unsigned char*  Wt8  = (unsigned char*)d_ws;                       // 3072*768 fp8
  unsigned short* embb = (unsigned short*)(Wt8 + (size_t)GNF * GK);  // NN*768 bf16
  unsigned char*  emb8 = (unsigned char*)(embb + (size_t)NN * GK);   // NN*768 fp8
  unsigned char*  x    = emb8 + (size_t)NN * GK;                     // NN*3072 fp8
  float* fregion = (float*)(x + (size_t)NN * GNF);
  float* wbuf   = fregion;                       // ETOT*2
  float* denom  = wbuf + (size_t)ETOT * 2;       // NN*2
  float* c      = denom + (size_t)NN * 2;        // NN*2
  float* t      = c + (size_t)NN * 2;            // HC
  float* pooled = t + HC;                        // HC
  float* cnt    = pooled + HC;                   // 1
  int zero_count = (int)(NN * 2 + NN * 2 + HC + HC + 1);

  // 0) zero accumulators (denom..cnt contiguous)
  zero_f32<<<128, 256, 0, stream>>>(denom, zero_count);

  // 0b) W -> Wt8 (fp8, transposed): rows 0..1535 = W_l cols, 1536..3071 = W_r
  dim3 tgrid(HC / 32, GK / 32);
  transpose_fp8<<<tgrid, 256, 0, stream>>>(W_l, Wt8);
  transpose_fp8<<<tgrid, 256, 0, stream>>>(W_r, Wt8 + (size_t)HC * GK);

  // 0c) emb -> {bf16, fp8} one pass
  cvt_emb<<<2048, 256, 0, stream>>>(emb, embb, emb8, NN * GK / 8);

  // 1) x = emb8 @ Wt8^T   (MX-fp8 MFMA, fp8 out)
  gemm_fp8<<<(NN / 128) * (GNF / 128), 256, 0, stream>>>(emb8, Wt8, x);

  // 2) edge logits + denom
  edge_logits<<<(ETOT + 3) / 4, 256, 0, stream>>>(x, edges, att, wbuf, denom);

  // 2b) mask count (independent)
  count_mask<<<32, 256, 0, stream>>>(mask, cnt);

  // 3) alpha -> c[src,h]
  alpha_scatter<<<(ETOT + 255) / 256, 256, 0, stream>>>(edges, mask, wbuf, denom, c);

  // 4) t = c^T @ emb  [2,768]  (pooled path stays high-precision)
  c_emb_gemv_b<<<NN / 128, 256, 0, stream>>>(embb, c, t);

  // 5) pooled = t @ W_l (per-head slice, exact fp32)
  pooled_gemv<<<HC / 256, 256, 0, stream>>>(t, W_l, pooled);

  // 6) finalize
  finalize<<<1, 64, 0, stream>>>(pooled, cnt, gbias, clsW, clsb, labels, out);
}